// Round 1
// baseline (827.936 us; speedup 1.0000x reference)
//
#include <hip/hip_runtime.h>
#include <math.h>

#define MAXT 4096

struct SelState {
  unsigned prefix;    // accumulated key bits of the k-th smallest element
  unsigned rank;      // remaining rank within current prefix (1-indexed)
  unsigned tieCount;  // number of elements whose key == prefix (after pass C)
  int cutoff;         // max index among selected ties
};

__device__ __forceinline__ unsigned keyOf(float f) {
  unsigned b = __float_as_uint(f);
  return b ^ ((b & 0x80000000u) ? 0xFFFFFFFFu : 0x80000000u);
}

__device__ __forceinline__ float waveMax(float v) {
#pragma unroll
  for (int o = 32; o >= 1; o >>= 1) v = fmaxf(v, __shfl_xor(v, o));
  return v;
}
__device__ __forceinline__ float waveSum(float v) {
#pragma unroll
  for (int o = 32; o >= 1; o >>= 1) v += __shfl_xor(v, o);
  return v;
}

// Zero histograms, init selection state. Must run before ce_kernel (which
// fuses the pass-A histogram).
__global__ __launch_bounds__(256) void init_kernel(unsigned* __restrict__ h1,
                                                   unsigned* __restrict__ h2,
                                                   SelState* st1, SelState* st2,
                                                   const int* __restrict__ numKeep) {
  int t = threadIdx.x;
  for (int j = t; j < 2048; j += 256) { h1[j] = 0u; h2[j] = 0u; }
  if (t == 0) {
    unsigned k = (unsigned)(*numKeep);
    st1->prefix = 0u; st1->rank = k; st1->tieCount = 0u; st1->cutoff = -1;
    st2->prefix = 0u; st2->rank = k; st2->tieCount = 0u; st2->cutoff = -1;
  }
}

// One wave per row, C = 1000 fp32 (250 float4). Computes per-sample CE loss
// for both nets and accumulates the pass-A (top 11 bits) histogram.
__global__ __launch_bounds__(256) void ce_kernel(
    const float* __restrict__ y1, const float* __restrict__ y2,
    const int* __restrict__ tgt,
    float* __restrict__ l1, float* __restrict__ l2,
    unsigned* __restrict__ h1, unsigned* __restrict__ h2, int N) {
  const float L2E = 1.4426950408889634f;
  const float LN2 = 0.6931471805599453f;
  int wid = threadIdx.x >> 6, lane = threadIdx.x & 63;
  int row = blockIdx.x * 4 + wid;
  if (row >= N) return;
  int t = tgt[row];
#pragma unroll
  for (int which = 0; which < 2; ++which) {
    const float* y = which ? y2 : y1;
    const float4* rp = (const float4*)(y + (size_t)row * 1000);
    float4 a = rp[lane];
    float4 b = rp[lane + 64];
    float4 c = rp[lane + 128];
    float4 d = make_float4(-INFINITY, -INFINITY, -INFINITY, -INFINITY);
    if (lane + 192 < 250) d = rp[lane + 192];
    float m = fmaxf(fmaxf(fmaxf(a.x, a.y), fmaxf(a.z, a.w)),
                    fmaxf(fmaxf(b.x, b.y), fmaxf(b.z, b.w)));
    m = fmaxf(m, fmaxf(fmaxf(c.x, c.y), fmaxf(c.z, c.w)));
    m = fmaxf(m, fmaxf(fmaxf(d.x, d.y), fmaxf(d.z, d.w)));
    m = waveMax(m);
    float s = exp2f((a.x - m) * L2E) + exp2f((a.y - m) * L2E) +
              exp2f((a.z - m) * L2E) + exp2f((a.w - m) * L2E) +
              exp2f((b.x - m) * L2E) + exp2f((b.y - m) * L2E) +
              exp2f((b.z - m) * L2E) + exp2f((b.w - m) * L2E) +
              exp2f((c.x - m) * L2E) + exp2f((c.y - m) * L2E) +
              exp2f((c.z - m) * L2E) + exp2f((c.w - m) * L2E) +
              exp2f((d.x - m) * L2E) + exp2f((d.y - m) * L2E) +
              exp2f((d.z - m) * L2E) + exp2f((d.w - m) * L2E);
    s = waveSum(s);
    if (lane == 0) {
      float xt = y[(size_t)row * 1000 + t];
      float loss = log2f(s) * LN2 + m - xt;
      (which ? l2 : l1)[row] = loss;
      atomicAdd(&(which ? h2 : h1)[keyOf(loss) >> 21], 1u);
    }
  }
}

// Histogram of next radix digit for elements matching the current prefix.
__global__ __launch_bounds__(256) void hist_kernel(
    const float* __restrict__ l1, const float* __restrict__ l2,
    unsigned* __restrict__ h1, unsigned* __restrict__ h2,
    const SelState* __restrict__ st1, const SelState* __restrict__ st2,
    int N, int shift, unsigned binMask, unsigned mmask) {
  unsigned p1 = st1->prefix, p2 = st2->prefix;
  for (int i = blockIdx.x * blockDim.x + threadIdx.x; i < N;
       i += gridDim.x * blockDim.x) {
    unsigned k1 = keyOf(l1[i]);
    if ((k1 & mmask) == p1) atomicAdd(&h1[(k1 >> shift) & binMask], 1u);
    unsigned k2 = keyOf(l2[i]);
    if ((k2 & mmask) == p2) atomicAdd(&h2[(k2 >> shift) & binMask], 1u);
  }
}

// Find the bin containing the remaining rank; update prefix/rank; zero hist.
// grid = 2 blocks (block 0 -> array 1, block 1 -> array 2).
__global__ __launch_bounds__(256) void scan_kernel(
    unsigned* __restrict__ h1, unsigned* __restrict__ h2,
    SelState* __restrict__ st1, SelState* __restrict__ st2,
    int shift, int nbits) {
  unsigned* h = blockIdx.x ? h2 : h1;
  SelState* st = blockIdx.x ? st2 : st1;
  int t = threadIdx.x;
  int bins = 1 << nbits;
  int per = bins >> 8;  // 8 (11 bits) or 4 (10 bits)
  unsigned r = st->rank;
  unsigned pfx = st->prefix;
  unsigned local[8];
  unsigned s = 0;
  for (int j = 0; j < per; ++j) { local[j] = h[t * per + j]; s += local[j]; }
  __shared__ unsigned sc[256];
  sc[t] = s;
  __syncthreads();
  for (int off = 1; off < 256; off <<= 1) {
    unsigned v = (t >= off) ? sc[t - off] : 0u;
    __syncthreads();
    sc[t] += v;
    __syncthreads();
  }
  unsigned incl = sc[t];
  unsigned excl = incl - s;
  if (excl < r && r <= incl) {
    unsigned cum = excl;
    for (int j = 0; j < per; ++j) {
      if (cum + local[j] >= r) {
        st->prefix = pfx | ((unsigned)(t * per + j) << shift);
        st->rank = r - cum;
        break;
      }
      cum += local[j];
    }
  }
  __syncthreads();
  for (int j = 0; j < per; ++j) h[t * per + j] = 0u;
}

// Collect indices of elements whose key equals the k-th smallest key.
__global__ __launch_bounds__(256) void tiecollect_kernel(
    const float* __restrict__ l1, const float* __restrict__ l2,
    SelState* st1, SelState* st2, int* __restrict__ t1, int* __restrict__ t2,
    int N) {
  unsigned K1 = st1->prefix, K2 = st2->prefix;
  for (int i = blockIdx.x * blockDim.x + threadIdx.x; i < N;
       i += gridDim.x * blockDim.x) {
    if (keyOf(l1[i]) == K1) {
      unsigned p = atomicAdd(&st1->tieCount, 1u);
      if (p < MAXT) t1[p] = i;
    }
    if (keyOf(l2[i]) == K2) {
      unsigned p = atomicAdd(&st2->tieCount, 1u);
      if (p < MAXT) t2[p] = i;
    }
  }
}

// Stable-argsort tie semantics: among equal keys, the smallest indices are
// selected first. cutoff = the (need)-th smallest tied index.
__global__ __launch_bounds__(256) void tierank_kernel(SelState* st1,
                                                      SelState* st2,
                                                      const int* __restrict__ t1,
                                                      const int* __restrict__ t2) {
  SelState* st = blockIdx.x ? st2 : st1;
  const int* ti = blockIdx.x ? t2 : t1;
  int T = min((int)st->tieCount, MAXT);
  int need = (int)st->rank;
  if (need >= T) {  // common case: unique k-th value (T==need==1) -> take all
    if (threadIdx.x == 0) st->cutoff = 0x7FFFFFFF;
    return;
  }
  for (int j = threadIdx.x; j < T; j += 256) {
    int idx = ti[j];
    int rk = 0;
    for (int m = 0; m < T; ++m) rk += (ti[m] < idx) ? 1 : 0;
    if (rk == need - 1) st->cutoff = idx;
  }
}

// Deterministic partial sums: per-block tree reduction, no float atomics.
__global__ __launch_bounds__(256) void partial_kernel(
    const float* __restrict__ l1, const float* __restrict__ l2,
    const SelState* __restrict__ st1, const SelState* __restrict__ st2,
    float* __restrict__ partials, int N) {
  unsigned K1 = st1->prefix, K2 = st2->prefix;
  int c1 = st1->cutoff, c2 = st2->cutoff;
  float s0 = 0.f, s1 = 0.f, s2 = 0.f, s3 = 0.f;
  for (int i = blockIdx.x * blockDim.x + threadIdx.x; i < N;
       i += gridDim.x * blockDim.x) {
    float f1 = l1[i], f2 = l2[i];
    unsigned k1 = keyOf(f1), k2 = keyOf(f2);
    bool sel1 = (k1 < K1) || (k1 == K1 && i <= c1);
    bool sel2 = (k2 < K2) || (k2 == K2 && i <= c2);
    if (sel2) s0 += f1;  // loss_1_update: loss_1 on net-2's selected set
    if (sel1) s1 += f2;  // loss_2_update: loss_2 on net-1's selected set
    s2 += f1;
    s3 += f2;
  }
  s0 = waveSum(s0); s1 = waveSum(s1); s2 = waveSum(s2); s3 = waveSum(s3);
  __shared__ float red[4][4];
  int wid = threadIdx.x >> 6, lane = threadIdx.x & 63;
  if (lane == 0) {
    red[wid][0] = s0; red[wid][1] = s1; red[wid][2] = s2; red[wid][3] = s3;
  }
  __syncthreads();
  if (threadIdx.x == 0) {
    for (int q = 0; q < 4; ++q)
      partials[blockIdx.x * 4 + q] =
          red[0][q] + red[1][q] + red[2][q] + red[3][q];
  }
}

__global__ __launch_bounds__(256) void final_kernel(
    const float* __restrict__ partials, const int* __restrict__ numKeep,
    float* __restrict__ out, int N, int nBlocks) {
  float s0 = 0.f, s1 = 0.f, s2 = 0.f, s3 = 0.f;
  for (int j = threadIdx.x; j < nBlocks; j += 256) {
    s0 += partials[j * 4 + 0];
    s1 += partials[j * 4 + 1];
    s2 += partials[j * 4 + 2];
    s3 += partials[j * 4 + 3];
  }
  s0 = waveSum(s0); s1 = waveSum(s1); s2 = waveSum(s2); s3 = waveSum(s3);
  __shared__ float red[4][4];
  int wid = threadIdx.x >> 6, lane = threadIdx.x & 63;
  if (lane == 0) {
    red[wid][0] = s0; red[wid][1] = s1; red[wid][2] = s2; red[wid][3] = s3;
  }
  __syncthreads();
  if (threadIdx.x == 0) {
    float a0 = red[0][0] + red[1][0] + red[2][0] + red[3][0];
    float a1 = red[0][1] + red[1][1] + red[2][1] + red[3][1];
    float a2 = red[0][2] + red[1][2] + red[2][2] + red[3][2];
    float a3 = red[0][3] + red[1][3] + red[2][3] + red[3][3];
    float k = (float)(*numKeep);
    out[0] = a0 / k;
    out[1] = a1 / k;
    out[2] = a2 / (float)N;
    out[3] = a3 / (float)N;
  }
}

extern "C" void kernel_launch(void* const* d_in, const int* in_sizes, int n_in,
                              void* d_out, int out_size, void* d_ws,
                              size_t ws_size, hipStream_t stream) {
  const float* y1 = (const float*)d_in[0];
  const float* y2 = (const float*)d_in[1];
  const int* tgt = (const int*)d_in[2];
  const int* numKeep = (const int*)d_in[3];
  int N = in_sizes[2];  // 65536 (C = in_sizes[0]/N = 1000, hardcoded in ce_kernel)
  float* out = (float*)d_out;

  // workspace layout
  float* l1 = (float*)d_ws;               // N fp32
  float* l2 = l1 + N;                     // N fp32
  unsigned* h1 = (unsigned*)(l2 + N);     // 2048
  unsigned* h2 = h1 + 2048;               // 2048
  SelState* st1 = (SelState*)(h2 + 2048);
  SelState* st2 = st1 + 1;
  int* t1 = (int*)(st2 + 1);              // MAXT
  int* t2 = t1 + MAXT;                    // MAXT
  float* partials = (float*)(t2 + MAXT);  // 256*4

  init_kernel<<<1, 256, 0, stream>>>(h1, h2, st1, st2, numKeep);
  ce_kernel<<<(N + 3) / 4, 256, 0, stream>>>(y1, y2, tgt, l1, l2, h1, h2, N);
  // radix select: pass A histogram was fused into ce_kernel (bits 31..21)
  scan_kernel<<<2, 256, 0, stream>>>(h1, h2, st1, st2, 21, 11);
  hist_kernel<<<256, 256, 0, stream>>>(l1, l2, h1, h2, st1, st2, N, 10, 2047u,
                                       0xFFE00000u);
  scan_kernel<<<2, 256, 0, stream>>>(h1, h2, st1, st2, 10, 11);
  hist_kernel<<<256, 256, 0, stream>>>(l1, l2, h1, h2, st1, st2, N, 0, 1023u,
                                       0xFFFFFC00u);
  scan_kernel<<<2, 256, 0, stream>>>(h1, h2, st1, st2, 0, 10);
  tiecollect_kernel<<<256, 256, 0, stream>>>(l1, l2, st1, st2, t1, t2, N);
  tierank_kernel<<<2, 256, 0, stream>>>(st1, st2, t1, t2);
  partial_kernel<<<256, 256, 0, stream>>>(l1, l2, st1, st2, partials, N);
  final_kernel<<<1, 256, 0, stream>>>(partials, numKeep, out, N, 256);
}

// Round 2
// 136.985 us; speedup vs baseline: 6.0440x; 6.0440x over previous
//
#include <hip/hip_runtime.h>
#include <math.h>

#define MAXT 4096

struct SelState {
  unsigned prefix;    // accumulated key bits of the k-th smallest element
  unsigned rank;      // remaining rank within current prefix (1-indexed)
  unsigned tieCount;  // number of elements whose key == prefix (after pass C)
  int cutoff;         // max index among selected ties
};

__device__ __forceinline__ unsigned keyOf(float f) {
  unsigned b = __float_as_uint(f);
  return b ^ ((b & 0x80000000u) ? 0xFFFFFFFFu : 0x80000000u);
}

__device__ __forceinline__ float waveMax(float v) {
#pragma unroll
  for (int o = 32; o >= 1; o >>= 1) v = fmaxf(v, __shfl_xor(v, o));
  return v;
}
__device__ __forceinline__ float waveSum(float v) {
#pragma unroll
  for (int o = 32; o >= 1; o >>= 1) v += __shfl_xor(v, o);
  return v;
}

// Zero histograms, init selection state.
__global__ __launch_bounds__(256) void init_kernel(unsigned* __restrict__ h1,
                                                   unsigned* __restrict__ h2,
                                                   SelState* st1, SelState* st2,
                                                   const int* __restrict__ numKeep) {
  int t = threadIdx.x;
  for (int j = t; j < 2048; j += 256) { h1[j] = 0u; h2[j] = 0u; }
  if (t == 0) {
    unsigned k = (unsigned)(*numKeep);
    st1->prefix = 0u; st1->rank = k; st1->tieCount = 0u; st1->cutoff = -1;
    st2->prefix = 0u; st2->rank = k; st2->tieCount = 0u; st2->cutoff = -1;
  }
}

// One wave per row, C = 1000 fp32 (250 float4). Pure CE loss, no atomics.
// y[row, t] is extracted from the registers already holding the row (one
// shuffle) instead of a dependent global re-load.
__global__ __launch_bounds__(256) void ce_kernel(
    const float* __restrict__ y1, const float* __restrict__ y2,
    const int* __restrict__ tgt,
    float* __restrict__ l1, float* __restrict__ l2, int N) {
  const float L2E = 1.4426950408889634f;
  const float LN2 = 0.6931471805599453f;
  int wid = threadIdx.x >> 6, lane = threadIdx.x & 63;
  int row = blockIdx.x * 4 + wid;
  if (row >= N) return;
  int t = tgt[row];
  int vecIdx = t >> 2;
  int grp = vecIdx >> 6;       // which of a/b/c/d holds element t (uniform)
  int srcLane = vecIdx & 63;   // uniform
  int comp = t & 3;            // uniform
#pragma unroll
  for (int which = 0; which < 2; ++which) {
    const float* y = which ? y2 : y1;
    const float4* rp = (const float4*)(y + (size_t)row * 1000);
    float4 a = rp[lane];
    float4 b = rp[lane + 64];
    float4 c = rp[lane + 128];
    float4 d = make_float4(-INFINITY, -INFINITY, -INFINITY, -INFINITY);
    if (lane + 192 < 250) d = rp[lane + 192];
    // extract y[row, t] from registers: every lane picks its candidate,
    // then broadcast from the owning lane.
    float4 sel = (grp == 0) ? a : (grp == 1) ? b : (grp == 2) ? c : d;
    float cand = (comp == 0) ? sel.x : (comp == 1) ? sel.y
               : (comp == 2) ? sel.z : sel.w;
    float xt = __shfl(cand, srcLane);
    float m = fmaxf(fmaxf(fmaxf(a.x, a.y), fmaxf(a.z, a.w)),
                    fmaxf(fmaxf(b.x, b.y), fmaxf(b.z, b.w)));
    m = fmaxf(m, fmaxf(fmaxf(c.x, c.y), fmaxf(c.z, c.w)));
    m = fmaxf(m, fmaxf(fmaxf(d.x, d.y), fmaxf(d.z, d.w)));
    m = waveMax(m);
    float s = exp2f((a.x - m) * L2E) + exp2f((a.y - m) * L2E) +
              exp2f((a.z - m) * L2E) + exp2f((a.w - m) * L2E) +
              exp2f((b.x - m) * L2E) + exp2f((b.y - m) * L2E) +
              exp2f((b.z - m) * L2E) + exp2f((b.w - m) * L2E) +
              exp2f((c.x - m) * L2E) + exp2f((c.y - m) * L2E) +
              exp2f((c.z - m) * L2E) + exp2f((c.w - m) * L2E) +
              exp2f((d.x - m) * L2E) + exp2f((d.y - m) * L2E) +
              exp2f((d.z - m) * L2E) + exp2f((d.w - m) * L2E);
    s = waveSum(s);
    if (lane == 0) {
      float loss = log2f(s) * LN2 + m - xt;
      (which ? l2 : l1)[row] = loss;
    }
  }
}

// Pass-A (top 11 bits) histogram with LDS privatization. Loss keys
// concentrate in a handful of top-bit bins, so per-element global atomics
// serialize on one cache line; per-block LDS aggregation reduces global
// atomic count to <= gridDim per hot bin.
__global__ __launch_bounds__(256) void histA_kernel(
    const float* __restrict__ l1, const float* __restrict__ l2,
    unsigned* __restrict__ h1, unsigned* __restrict__ h2, int N) {
  __shared__ unsigned lh[2][2048];
  int t = threadIdx.x;
  for (int j = t; j < 2048; j += 256) { lh[0][j] = 0u; lh[1][j] = 0u; }
  __syncthreads();
  for (int i = blockIdx.x * blockDim.x + t; i < N;
       i += gridDim.x * blockDim.x) {
    atomicAdd(&lh[0][keyOf(l1[i]) >> 21], 1u);
    atomicAdd(&lh[1][keyOf(l2[i]) >> 21], 1u);
  }
  __syncthreads();
  for (int j = t; j < 2048; j += 256) {
    unsigned v0 = lh[0][j], v1 = lh[1][j];
    if (v0) atomicAdd(&h1[j], v0);
    if (v1) atomicAdd(&h2[j], v1);
  }
}

// Histogram of next radix digit for elements matching the current prefix.
// (Digit bits here are mantissa bits -> well spread; per-element atomics OK.)
__global__ __launch_bounds__(256) void hist_kernel(
    const float* __restrict__ l1, const float* __restrict__ l2,
    unsigned* __restrict__ h1, unsigned* __restrict__ h2,
    const SelState* __restrict__ st1, const SelState* __restrict__ st2,
    int N, int shift, unsigned binMask, unsigned mmask) {
  unsigned p1 = st1->prefix, p2 = st2->prefix;
  for (int i = blockIdx.x * blockDim.x + threadIdx.x; i < N;
       i += gridDim.x * blockDim.x) {
    unsigned k1 = keyOf(l1[i]);
    if ((k1 & mmask) == p1) atomicAdd(&h1[(k1 >> shift) & binMask], 1u);
    unsigned k2 = keyOf(l2[i]);
    if ((k2 & mmask) == p2) atomicAdd(&h2[(k2 >> shift) & binMask], 1u);
  }
}

// Find the bin containing the remaining rank; update prefix/rank; zero hist.
// grid = 2 blocks (block 0 -> array 1, block 1 -> array 2).
__global__ __launch_bounds__(256) void scan_kernel(
    unsigned* __restrict__ h1, unsigned* __restrict__ h2,
    SelState* __restrict__ st1, SelState* __restrict__ st2,
    int shift, int nbits) {
  unsigned* h = blockIdx.x ? h2 : h1;
  SelState* st = blockIdx.x ? st2 : st1;
  int t = threadIdx.x;
  int bins = 1 << nbits;
  int per = bins >> 8;  // 8 (11 bits) or 4 (10 bits)
  unsigned r = st->rank;
  unsigned pfx = st->prefix;
  unsigned local[8];
  unsigned s = 0;
  for (int j = 0; j < per; ++j) { local[j] = h[t * per + j]; s += local[j]; }
  __shared__ unsigned sc[256];
  sc[t] = s;
  __syncthreads();
  for (int off = 1; off < 256; off <<= 1) {
    unsigned v = (t >= off) ? sc[t - off] : 0u;
    __syncthreads();
    sc[t] += v;
    __syncthreads();
  }
  unsigned incl = sc[t];
  unsigned excl = incl - s;
  if (excl < r && r <= incl) {
    unsigned cum = excl;
    for (int j = 0; j < per; ++j) {
      if (cum + local[j] >= r) {
        st->prefix = pfx | ((unsigned)(t * per + j) << shift);
        st->rank = r - cum;
        break;
      }
      cum += local[j];
    }
  }
  __syncthreads();
  for (int j = 0; j < per; ++j) h[t * per + j] = 0u;
}

// Collect indices of elements whose key equals the k-th smallest key.
__global__ __launch_bounds__(256) void tiecollect_kernel(
    const float* __restrict__ l1, const float* __restrict__ l2,
    SelState* st1, SelState* st2, int* __restrict__ t1, int* __restrict__ t2,
    int N) {
  unsigned K1 = st1->prefix, K2 = st2->prefix;
  for (int i = blockIdx.x * blockDim.x + threadIdx.x; i < N;
       i += gridDim.x * blockDim.x) {
    if (keyOf(l1[i]) == K1) {
      unsigned p = atomicAdd(&st1->tieCount, 1u);
      if (p < MAXT) t1[p] = i;
    }
    if (keyOf(l2[i]) == K2) {
      unsigned p = atomicAdd(&st2->tieCount, 1u);
      if (p < MAXT) t2[p] = i;
    }
  }
}

// Stable-argsort tie semantics: among equal keys, the smallest indices are
// selected first. cutoff = the (need)-th smallest tied index.
__global__ __launch_bounds__(256) void tierank_kernel(SelState* st1,
                                                      SelState* st2,
                                                      const int* __restrict__ t1,
                                                      const int* __restrict__ t2) {
  SelState* st = blockIdx.x ? st2 : st1;
  const int* ti = blockIdx.x ? t2 : t1;
  int T = min((int)st->tieCount, MAXT);
  int need = (int)st->rank;
  if (need >= T) {  // common case: unique k-th value (T==need==1) -> take all
    if (threadIdx.x == 0) st->cutoff = 0x7FFFFFFF;
    return;
  }
  for (int j = threadIdx.x; j < T; j += 256) {
    int idx = ti[j];
    int rk = 0;
    for (int m = 0; m < T; ++m) rk += (ti[m] < idx) ? 1 : 0;
    if (rk == need - 1) st->cutoff = idx;
  }
}

// Deterministic partial sums: per-block tree reduction, no float atomics.
__global__ __launch_bounds__(256) void partial_kernel(
    const float* __restrict__ l1, const float* __restrict__ l2,
    const SelState* __restrict__ st1, const SelState* __restrict__ st2,
    float* __restrict__ partials, int N) {
  unsigned K1 = st1->prefix, K2 = st2->prefix;
  int c1 = st1->cutoff, c2 = st2->cutoff;
  float s0 = 0.f, s1 = 0.f, s2 = 0.f, s3 = 0.f;
  for (int i = blockIdx.x * blockDim.x + threadIdx.x; i < N;
       i += gridDim.x * blockDim.x) {
    float f1 = l1[i], f2 = l2[i];
    unsigned k1 = keyOf(f1), k2 = keyOf(f2);
    bool sel1 = (k1 < K1) || (k1 == K1 && i <= c1);
    bool sel2 = (k2 < K2) || (k2 == K2 && i <= c2);
    if (sel2) s0 += f1;  // loss_1_update: loss_1 on net-2's selected set
    if (sel1) s1 += f2;  // loss_2_update: loss_2 on net-1's selected set
    s2 += f1;
    s3 += f2;
  }
  s0 = waveSum(s0); s1 = waveSum(s1); s2 = waveSum(s2); s3 = waveSum(s3);
  __shared__ float red[4][4];
  int wid = threadIdx.x >> 6, lane = threadIdx.x & 63;
  if (lane == 0) {
    red[wid][0] = s0; red[wid][1] = s1; red[wid][2] = s2; red[wid][3] = s3;
  }
  __syncthreads();
  if (threadIdx.x == 0) {
    for (int q = 0; q < 4; ++q)
      partials[blockIdx.x * 4 + q] =
          red[0][q] + red[1][q] + red[2][q] + red[3][q];
  }
}

__global__ __launch_bounds__(256) void final_kernel(
    const float* __restrict__ partials, const int* __restrict__ numKeep,
    float* __restrict__ out, int N, int nBlocks) {
  float s0 = 0.f, s1 = 0.f, s2 = 0.f, s3 = 0.f;
  for (int j = threadIdx.x; j < nBlocks; j += 256) {
    s0 += partials[j * 4 + 0];
    s1 += partials[j * 4 + 1];
    s2 += partials[j * 4 + 2];
    s3 += partials[j * 4 + 3];
  }
  s0 = waveSum(s0); s1 = waveSum(s1); s2 = waveSum(s2); s3 = waveSum(s3);
  __shared__ float red[4][4];
  int wid = threadIdx.x >> 6, lane = threadIdx.x & 63;
  if (lane == 0) {
    red[wid][0] = s0; red[wid][1] = s1; red[wid][2] = s2; red[wid][3] = s3;
  }
  __syncthreads();
  if (threadIdx.x == 0) {
    float a0 = red[0][0] + red[1][0] + red[2][0] + red[3][0];
    float a1 = red[0][1] + red[1][1] + red[2][1] + red[3][1];
    float a2 = red[0][2] + red[1][2] + red[2][2] + red[3][2];
    float a3 = red[0][3] + red[1][3] + red[2][3] + red[3][3];
    float k = (float)(*numKeep);
    out[0] = a0 / k;
    out[1] = a1 / k;
    out[2] = a2 / (float)N;
    out[3] = a3 / (float)N;
  }
}

extern "C" void kernel_launch(void* const* d_in, const int* in_sizes, int n_in,
                              void* d_out, int out_size, void* d_ws,
                              size_t ws_size, hipStream_t stream) {
  const float* y1 = (const float*)d_in[0];
  const float* y2 = (const float*)d_in[1];
  const int* tgt = (const int*)d_in[2];
  const int* numKeep = (const int*)d_in[3];
  int N = in_sizes[2];  // 65536 (C = 1000 hardcoded in ce_kernel)
  float* out = (float*)d_out;

  // workspace layout
  float* l1 = (float*)d_ws;               // N fp32
  float* l2 = l1 + N;                     // N fp32
  unsigned* h1 = (unsigned*)(l2 + N);     // 2048
  unsigned* h2 = h1 + 2048;               // 2048
  SelState* st1 = (SelState*)(h2 + 2048);
  SelState* st2 = st1 + 1;
  int* t1 = (int*)(st2 + 1);              // MAXT
  int* t2 = t1 + MAXT;                    // MAXT
  float* partials = (float*)(t2 + MAXT);  // 256*4

  init_kernel<<<1, 256, 0, stream>>>(h1, h2, st1, st2, numKeep);
  ce_kernel<<<(N + 3) / 4, 256, 0, stream>>>(y1, y2, tgt, l1, l2, N);
  // radix select over order-preserving key bits: 11 + 11 + 10
  histA_kernel<<<256, 256, 0, stream>>>(l1, l2, h1, h2, N);
  scan_kernel<<<2, 256, 0, stream>>>(h1, h2, st1, st2, 21, 11);
  hist_kernel<<<256, 256, 0, stream>>>(l1, l2, h1, h2, st1, st2, N, 10, 2047u,
                                       0xFFE00000u);
  scan_kernel<<<2, 256, 0, stream>>>(h1, h2, st1, st2, 10, 11);
  hist_kernel<<<256, 256, 0, stream>>>(l1, l2, h1, h2, st1, st2, N, 0, 1023u,
                                       0xFFFFFC00u);
  scan_kernel<<<2, 256, 0, stream>>>(h1, h2, st1, st2, 0, 10);
  tiecollect_kernel<<<256, 256, 0, stream>>>(l1, l2, st1, st2, t1, t2, N);
  tierank_kernel<<<2, 256, 0, stream>>>(st1, st2, t1, t2);
  partial_kernel<<<256, 256, 0, stream>>>(l1, l2, st1, st2, partials, N);
  final_kernel<<<1, 256, 0, stream>>>(partials, numKeep, out, N, 256);
}